// Round 1
// baseline (1278.425 us; speedup 1.0000x reference)
//
#include <hip/hip_runtime.h>
#include <math.h>

// DotProductAttention: B=2, H=16, S=2048, D=64, fp32 in/out, int32 mask (B,1,S,S).
// Flash-style online softmax, one thread per query row, K/V tiles in LDS.
// Round 0: fp32 VALU correctness anchor. VALU roofline ~219us for 34.4 GFLOP.

#define B_ 2
#define H_ 16
#define S_ 2048
#define D_ 64
#define BC 64   // key tile size (LDS: 2 * 64*64*4 = 32 KB)

__global__ __launch_bounds__(256, 1)
void attn_fwd(const float* __restrict__ qg, const float* __restrict__ kg,
              const float* __restrict__ vg, const int* __restrict__ maskg,
              float* __restrict__ outg) {
  const int bh = blockIdx.y;             // 0..B*H-1
  const int b  = bh >> 4;                // bh / H
  const int qi = blockIdx.x * 256 + threadIdx.x;   // this thread's query row

  __shared__ float sK[BC][D_];
  __shared__ float sV[BC][D_];

  // q row -> registers, pre-scaled by 1/sqrt(D)=0.125 (folds the score scale)
  const float* qrow = qg + ((size_t)bh * S_ + qi) * D_;
  float4 q4[16];
#pragma unroll
  for (int i = 0; i < 16; ++i) {
    float4 t = ((const float4*)qrow)[i];
    t.x *= 0.125f; t.y *= 0.125f; t.z *= 0.125f; t.w *= 0.125f;
    q4[i] = t;
  }

  float4 o4[16];
#pragma unroll
  for (int i = 0; i < 16; ++i) o4[i] = make_float4(0.f, 0.f, 0.f, 0.f);
  // -1e30 sentinel (not -inf: avoids inf arithmetic under fast-math).
  // exp(-1e30 - s) underflows to exactly 0, so the first real key cleanly
  // wipes the zero accumulator; all-masked prefixes reproduce the
  // reference's uniform-softmax-over--1e9 behavior exactly.
  float m = -1e30f, l = 0.f;

  const int*   mrow  = maskg + ((size_t)b * S_ + qi) * S_;
  const float* kbase = kg + (size_t)bh * S_ * D_;
  const float* vbase = vg + (size_t)bh * S_ * D_;

  for (int t0 = 0; t0 < S_; t0 += BC) {
    __syncthreads();
    {
      // cooperative tile load: 64 keys * 64 floats = 1024 float4 per tensor,
      // 256 threads * 4 float4 each, fully coalesced
      const float4* ksrc = (const float4*)(kbase + (size_t)t0 * D_);
      const float4* vsrc = (const float4*)(vbase + (size_t)t0 * D_);
      float4* kdst = (float4*)&sK[0][0];
      float4* vdst = (float4*)&sV[0][0];
#pragma unroll
      for (int i = 0; i < 4; ++i) {
        const int idx = threadIdx.x + 256 * i;
        kdst[idx] = ksrc[idx];
        vdst[idx] = vsrc[idx];
      }
    }
    __syncthreads();

    for (int j = 0; j < BC; j += 4) {
      const int4 mk = *(const int4*)(mrow + t0 + j);   // 4 mask vals, own row
#pragma unroll
      for (int jj = 0; jj < 4; ++jj) {
        const int msk = (jj == 0) ? mk.x : (jj == 1) ? mk.y
                      : (jj == 2) ? mk.z : mk.w;
        // dot(q, k_j): all lanes read the same LDS row -> broadcast, free
        const float4* krow = (const float4*)sK[j + jj];
        float sx = 0.f, sy = 0.f, sz = 0.f, sw = 0.f;
#pragma unroll
        for (int i = 0; i < 16; ++i) {
          const float4 kk = krow[i];
          sx = fmaf(q4[i].x, kk.x, sx);
          sy = fmaf(q4[i].y, kk.y, sy);
          sz = fmaf(q4[i].z, kk.z, sz);
          sw = fmaf(q4[i].w, kk.w, sw);
        }
        float s = (sx + sy) + (sz + sw);
        s = msk ? s : -1e9f;            // exact reference mask semantics

        // deferred-rescale online softmax: only pay the 64-mul rescale when
        // the running max actually moves (~14% of wave-steps)
        if (s > m) {
          const float alpha = __expf(m - s);
          l *= alpha;
#pragma unroll
          for (int i = 0; i < 16; ++i) {
            o4[i].x *= alpha; o4[i].y *= alpha;
            o4[i].z *= alpha; o4[i].w *= alpha;
          }
          m = s;
        }
        const float p = __expf(s - m);
        l += p;

        const float4* vrow = (const float4*)sV[j + jj];  // broadcast again
#pragma unroll
        for (int i = 0; i < 16; ++i) {
          const float4 vv = vrow[i];
          o4[i].x = fmaf(p, vv.x, o4[i].x);
          o4[i].y = fmaf(p, vv.y, o4[i].y);
          o4[i].z = fmaf(p, vv.z, o4[i].z);
          o4[i].w = fmaf(p, vv.w, o4[i].w);
        }
      }
    }
  }

  const float linv = 1.0f / l;
  float4* orow = (float4*)(outg + ((size_t)bh * S_ + qi) * D_);
#pragma unroll
  for (int i = 0; i < 16; ++i) {
    float4 t = o4[i];
    t.x *= linv; t.y *= linv; t.z *= linv; t.w *= linv;
    orow[i] = t;
  }
}

extern "C" void kernel_launch(void* const* d_in, const int* in_sizes, int n_in,
                              void* d_out, int out_size, void* d_ws, size_t ws_size,
                              hipStream_t stream) {
  const float* q    = (const float*)d_in[0];
  const float* k    = (const float*)d_in[1];
  const float* v    = (const float*)d_in[2];
  const int*   mask = (const int*)d_in[3];
  float* out = (float*)d_out;

  dim3 grid(S_ / 256, B_ * H_);   // (8, 32) = 256 blocks
  attn_fwd<<<grid, 256, 0, stream>>>(q, k, v, mask, out);
}

// Round 3
// 236.360 us; speedup vs baseline: 5.4088x; 5.4088x over previous
//
#include <hip/hip_runtime.h>
#include <hip/hip_bf16.h>

// DotProductAttention B=2,H=16,S=2048,D=64 fp32 in/out, int32 mask (B,1,S,S).
// R2: MFMA flash attention (R1 structure) + FIX: reduce lsum across the 4
//     quad-replicas before folding into l. R1's l held only 16/64 keys per
//     lane -> output ~4x too large (absmax 2.33).
//  - S^T = K*Q^T so softmax stats live one-query-per-lane-column (2 shuffles).
//  - base-2 softmax (scale 0.125*log2e folded into Q, mask -> -1e9*log2e).
//  - P: C-layout -> A-layout via per-wave LDS round trip (m120 pattern).
//  - V transposed in LDS [d][key] so PV B-frags are ds_read_b128.
//  - all LDS rows 144 B (72 bf16): 16B-aligned for b128, bank-balanced.

#define B_ 2
#define H_ 16
#define S_ 2048
#define D_ 64
#define BQ 64
#define BK 64
#define PADW 72   // LDS row stride in bf16 elems (144 bytes)

typedef __attribute__((ext_vector_type(4))) float f32x4;
typedef __attribute__((ext_vector_type(8))) short bf16x8;
typedef __attribute__((ext_vector_type(4))) short bf16x4;

#define QSCALE 0.1803368801111137f       // 0.125 * log2(e)
#define MASKNEG (-1.4426950408889634e9f) // -1e9 * log2(e)

static __device__ __forceinline__ short f2bf(float f) {
  __hip_bfloat16 h = __float2bfloat16(f);
  short s; __builtin_memcpy(&s, &h, sizeof(s)); return s;
}
static __device__ __forceinline__ float fexp2(float x) {
  return __builtin_amdgcn_exp2f(x);
}

__global__ __launch_bounds__(256, 4)
void attn_mfma(const float* __restrict__ qg, const float* __restrict__ kg,
               const float* __restrict__ vg, const int* __restrict__ maskg,
               float* __restrict__ outg) {
  __shared__ short sK[BK][PADW];      // [key][d]   bf16
  __shared__ short sVT[D_][PADW];     // [d][key]   bf16 (transposed V)
  __shared__ short sP[4][16][PADW];   // per-wave P [q][key] bf16

  const int tid  = threadIdx.x;
  const int lane = tid & 63;
  const int wv   = tid >> 6;
  const int l15  = lane & 15;
  const int quad = lane >> 4;

  const int bh = blockIdx.y;          // 0..31
  const int b  = bh >> 4;
  const int q0 = blockIdx.x * BQ;
  const int qw = q0 + wv * 16 + l15;  // this lane's stats-query row

  // ---- Q fragments (B-operand: lane holds Q[q=l15][d=ks*32+quad*8+j]) ----
  bf16x8 qf[2];
  {
    const float* qrow = qg + ((size_t)bh * S_ + qw) * D_;
    #pragma unroll
    for (int ks = 0; ks < 2; ++ks) {
      const float4 u0 = *(const float4*)(qrow + ks*32 + quad*8);
      const float4 u1 = *(const float4*)(qrow + ks*32 + quad*8 + 4);
      bf16x8 f;
      f[0]=f2bf(u0.x*QSCALE); f[1]=f2bf(u0.y*QSCALE);
      f[2]=f2bf(u0.z*QSCALE); f[3]=f2bf(u0.w*QSCALE);
      f[4]=f2bf(u1.x*QSCALE); f[5]=f2bf(u1.y*QSCALE);
      f[6]=f2bf(u1.z*QSCALE); f[7]=f2bf(u1.w*QSCALE);
      qf[ks] = f;
    }
  }

  f32x4 O[4];
  #pragma unroll
  for (int dt = 0; dt < 4; ++dt) O[dt] = (f32x4){0.f, 0.f, 0.f, 0.f};
  float m = -3.0e38f, l = 0.f;

  const float* kbase = kg + (size_t)bh * S_ * D_;
  const float* vbase = vg + (size_t)bh * S_ * D_;
  const int*   mrow  = maskg + ((size_t)b * S_ + qw) * S_;

  for (int t0 = 0; t0 < S_; t0 += BK) {
    __syncthreads();
    // ---- stage K tile [key][d], fp32->bf16, coalesced float4, b64 writes ----
    #pragma unroll
    for (int i = 0; i < 4; ++i) {
      const int id = tid + 256*i;
      const int key = id >> 4, d4 = (id & 15) * 4;
      const float4 u = *(const float4*)(kbase + (size_t)(t0 + key)*D_ + d4);
      bf16x4 w; w[0]=f2bf(u.x); w[1]=f2bf(u.y); w[2]=f2bf(u.z); w[3]=f2bf(u.w);
      *(bf16x4*)&sK[key][d4] = w;
    }
    // ---- stage V^T tile [d][key]: key-pairs packed as b32 writes ----
    #pragma unroll
    for (int i = 0; i < 2; ++i) {
      const int id = tid + 256*i;
      const int kp = id & 31, d4 = (id >> 5) * 4;
      const float4 a = *(const float4*)(vbase + (size_t)(t0 + 2*kp    )*D_ + d4);
      const float4 c = *(const float4*)(vbase + (size_t)(t0 + 2*kp + 1)*D_ + d4);
      const float av[4] = {a.x, a.y, a.z, a.w};
      const float cv[4] = {c.x, c.y, c.z, c.w};
      #pragma unroll
      for (int j = 0; j < 4; ++j) {
        const unsigned pk = (unsigned)(unsigned short)f2bf(av[j])
                          | ((unsigned)(unsigned short)f2bf(cv[j]) << 16);
        *(unsigned*)&sVT[d4 + j][2*kp] = pk;
      }
    }
    __syncthreads();

    // ---- mask for this lane's q row, 64 keys ----
    int4 mk[4];
    #pragma unroll
    for (int mt = 0; mt < 4; ++mt)
      mk[mt] = *(const int4*)(mrow + t0 + mt*16 + quad*4);

    // ---- S^T = K * Q^T : C[row=key=quad*4+r (tile mt)][col=q=l15] ----
    f32x4 st[4];
    #pragma unroll
    for (int mt = 0; mt < 4; ++mt) {
      f32x4 acc = (f32x4){0.f, 0.f, 0.f, 0.f};
      #pragma unroll
      for (int ks = 0; ks < 2; ++ks) {
        const bf16x8 kf = *(const bf16x8*)&sK[mt*16 + l15][ks*32 + quad*8];
        acc = __builtin_amdgcn_mfma_f32_16x16x32_bf16(kf, qf[ks], acc, 0, 0, 0);
      }
      st[mt] = acc;
    }

    // ---- mask + chunk max ----
    float cmax = -3.0e38f;
    #pragma unroll
    for (int mt = 0; mt < 4; ++mt) {
      f32x4 s = st[mt];
      s.x = mk[mt].x ? s.x : MASKNEG;
      s.y = mk[mt].y ? s.y : MASKNEG;
      s.z = mk[mt].z ? s.z : MASKNEG;
      s.w = mk[mt].w ? s.w : MASKNEG;
      st[mt] = s;
      cmax = fmaxf(cmax, fmaxf(fmaxf(s.x, s.y), fmaxf(s.z, s.w)));
    }
    cmax = fmaxf(cmax, __shfl_xor(cmax, 16));
    cmax = fmaxf(cmax, __shfl_xor(cmax, 32));
    const float mnew  = fmaxf(m, cmax);
    const float alpha = fexp2(m - mnew);   // ==0 on first chunk (m=-3e38)
    m = mnew;

    // ---- P = exp2(S - m), accumulate l, write P to per-wave LDS ----
    float lsum = 0.f;
    #pragma unroll
    for (int mt = 0; mt < 4; ++mt) {
      const float p0 = fexp2(st[mt].x - mnew);
      const float p1 = fexp2(st[mt].y - mnew);
      const float p2 = fexp2(st[mt].z - mnew);
      const float p3 = fexp2(st[mt].w - mnew);
      lsum += (p0 + p1) + (p2 + p3);
      bf16x4 pw; pw[0]=f2bf(p0); pw[1]=f2bf(p1); pw[2]=f2bf(p2); pw[3]=f2bf(p3);
      *(bf16x4*)&sP[wv][l15][mt*16 + quad*4] = pw;
    }
    // R2 FIX: each quad-replica of query l15 holds only 16/64 chunk keys.
    // Reduce the partial sums across quads before updating l.
    lsum += __shfl_xor(lsum, 16);
    lsum += __shfl_xor(lsum, 32);
    l = l * alpha + lsum;

    // ---- rescale O (O-rows are q=quad*4+r; fetch alpha from stats lanes) ----
    const float ar0 = __shfl(alpha, quad*4 + 0);
    const float ar1 = __shfl(alpha, quad*4 + 1);
    const float ar2 = __shfl(alpha, quad*4 + 2);
    const float ar3 = __shfl(alpha, quad*4 + 3);
    #pragma unroll
    for (int dt = 0; dt < 4; ++dt) {
      O[dt].x *= ar0; O[dt].y *= ar1; O[dt].z *= ar2; O[dt].w *= ar3;
    }

    // wave-internal: drain ds_writes (cross-lane visibility within the wave)
    asm volatile("s_waitcnt lgkmcnt(0)" ::: "memory");

    // ---- O += P * V ----
    const bf16x8 pf0 = *(const bf16x8*)&sP[wv][l15][quad*8];
    const bf16x8 pf1 = *(const bf16x8*)&sP[wv][l15][32 + quad*8];
    #pragma unroll
    for (int dt = 0; dt < 4; ++dt) {
      const bf16x8 vf0 = *(const bf16x8*)&sVT[dt*16 + l15][quad*8];
      const bf16x8 vf1 = *(const bf16x8*)&sVT[dt*16 + l15][32 + quad*8];
      O[dt] = __builtin_amdgcn_mfma_f32_16x16x32_bf16(pf0, vf0, O[dt], 0, 0, 0);
      O[dt] = __builtin_amdgcn_mfma_f32_16x16x32_bf16(pf1, vf1, O[dt], 0, 0, 0);
    }
  }

  // ---- epilogue: normalize by l (per O-row), store ----
  float ir[4];
  #pragma unroll
  for (int r = 0; r < 4; ++r) ir[r] = 1.0f / __shfl(l, quad*4 + r);

  float* ob = outg + ((size_t)bh * S_ + q0 + wv*16) * D_;
  #pragma unroll
  for (int dt = 0; dt < 4; ++dt) {
    ob[(quad*4 + 0)*D_ + dt*16 + l15] = O[dt].x * ir[0];
    ob[(quad*4 + 1)*D_ + dt*16 + l15] = O[dt].y * ir[1];
    ob[(quad*4 + 2)*D_ + dt*16 + l15] = O[dt].z * ir[2];
    ob[(quad*4 + 3)*D_ + dt*16 + l15] = O[dt].w * ir[3];
  }
}

extern "C" void kernel_launch(void* const* d_in, const int* in_sizes, int n_in,
                              void* d_out, int out_size, void* d_ws, size_t ws_size,
                              hipStream_t stream) {
  const float* q    = (const float*)d_in[0];
  const float* k    = (const float*)d_in[1];
  const float* v    = (const float*)d_in[2];
  const int*   mask = (const int*)d_in[3];
  float* out = (float*)d_out;

  dim3 grid(S_ / BQ, B_ * H_);   // (32, 32) = 1024 blocks, 4 waves each
  attn_mfma<<<grid, 256, 0, stream>>>(q, k, v, mask, out);
}